// Round 17
// baseline (381.421 us; speedup 1.0000x reference)
//
#include <hip/hip_runtime.h>
#include <cstdint>
#include <cstddef>

// ---------------- types ----------------
typedef short short4v __attribute__((ext_vector_type(4)));
typedef short short8v __attribute__((ext_vector_type(8)));
typedef float f32x4   __attribute__((ext_vector_type(4)));

#define T_LEN  2048
#define HDIM   4096
#define NHEADS 32
#define HEADD  128
#define QKVN   4608   // (32 + 2*2) * 128

static __device__ __forceinline__ short f2bf(float f) {
  __bf16 h = (__bf16)f;               // RNE fptrunc
  return __builtin_bit_cast(short, h);
}
static __device__ __forceinline__ float bf2f(short u) {
  return __builtin_bit_cast(float, ((unsigned int)(unsigned short)u) << 16);  // exact
}

static __device__ __forceinline__ void gload_lds16(const void* g, void* l) {
  // async global->LDS, 16B per lane; LDS dest is wave-uniform base + lane*16
  __builtin_amdgcn_global_load_lds((const __attribute__((address_space(1))) void*)g,
                                   (__attribute__((address_space(3))) void*)l,
                                   16, 0, 0);
}

// ---------------- fused cast: hidden + w_qkv in one launch ----------------
__global__ void cast_pair(const float* __restrict__ a, short* __restrict__ oa, int na4,
                          const float* __restrict__ b, short* __restrict__ ob, int nb4) {
  int idx = blockIdx.x * blockDim.x + threadIdx.x;
  int stride = gridDim.x * blockDim.x;
  const int ntot = na4 + nb4;
  for (int i = idx; i < ntot; i += stride) {
    const float4* src = (i < na4) ? ((const float4*)a + i) : ((const float4*)b + (i - na4));
    short4v* dst      = (i < na4) ? ((short4v*)oa + i)     : ((short4v*)ob + (i - na4));
    float4 v = *src;
    short4v o;
    o[0] = f2bf(v.x); o[1] = f2bf(v.y); o[2] = f2bf(v.z); o[3] = f2bf(v.w);
    *dst = o;
  }
}

// ---------------- split-K GEMM: Cp[z] = A[:, zK/2:(z+1)K/2] * B^T ----------
// 128x128 tile, BK=32 dbuf, prefetch-before-compute, T1 XCD swizzle.
// grid (N/128, M/128, 2); per-CU blocks 4-4.5 -> 2x MFMA issue per latency
// window vs R12's 2 blocks (per-wave density UNCHANGED, unlike R15).
// Writes bf16 partials (bias folded into the reduce pass).
__global__ __launch_bounds__(256, 2) void gemm_splitk(
    const short* __restrict__ A,     // [M][K] bf16
    const short* __restrict__ B,     // [N][K] bf16
    short* __restrict__ Cp,          // [2][M][N] bf16 partials
    int M, int N, int K)
{
  __shared__ short sA[2][128 * 32];
  __shared__ short sB[2][128 * 32];
  const int tid  = threadIdx.x;
  const int lane = tid & 63;
  const int wv   = tid >> 6;
  const int wr   = wv >> 1;
  const int wc   = wv & 1;
  const int z    = blockIdx.z;
  const int Khalf = K >> 1;

  const int nwg  = gridDim.x * gridDim.y;
  int wgid = blockIdx.y * gridDim.x + blockIdx.x;
  wgid = (wgid & 7) * (nwg >> 3) + (wgid >> 3);
  const int bn0 = (wgid / gridDim.y) * 128;
  const int bm0 = (wgid % gridDim.y) * 128;

  const int row0 = tid >> 2;
  const int kc0  = (tid & 3) * 8;
  const int row1 = row0 + 64;
  const short* gA0 = A + (size_t)(bm0 + row0) * K + z * Khalf + kc0;
  const short* gA1 = A + (size_t)(bm0 + row1) * K + z * Khalf + kc0;
  const short* gB0 = B + (size_t)(bn0 + row0) * K + z * Khalf + kc0;
  const short* gB1 = B + (size_t)(bn0 + row1) * K + z * Khalf + kc0;

  const int fr = lane & 15;
  const int fk = (lane >> 4) * 8;

  auto STAGE = [&](int b, int kt) {
    short* lA = &sA[b][0] + wv * 64 * 8;
    short* lB = &sB[b][0] + wv * 64 * 8;
    gload_lds16(gA0 + kt, lA);
    gload_lds16(gA1 + kt, lA + 256 * 8);
    gload_lds16(gB0 + kt, lB);
    gload_lds16(gB1 + kt, lB + 256 * 8);
  };

  f32x4 zero = {0.f, 0.f, 0.f, 0.f};
  f32x4 acc[4][4];
#pragma unroll
  for (int m = 0; m < 4; m++)
#pragma unroll
    for (int n = 0; n < 4; n++) acc[m][n] = zero;

  int cur = 0;
  STAGE(0, 0);
  __syncthreads();

  for (int kt = 0; kt < Khalf; kt += 32) {
    if (kt + 32 < Khalf) STAGE(cur ^ 1, kt + 32);
    const short* aB = &sA[cur][0];
    const short* bB = &sB[cur][0];
    short8v af[4], bfr[4];
#pragma unroll
    for (int m = 0; m < 4; m++)
      af[m] = *(const short8v*)(aB + (wr * 64 + m * 16 + fr) * 32 + fk);
#pragma unroll
    for (int n = 0; n < 4; n++)
      bfr[n] = *(const short8v*)(bB + (wc * 64 + n * 16 + fr) * 32 + fk);
#pragma unroll
    for (int m = 0; m < 4; m++)
#pragma unroll
      for (int n = 0; n < 4; n++)
        acc[m][n] = __builtin_amdgcn_mfma_f32_16x16x32_bf16(af[m], bfr[n], acc[m][n], 0, 0, 0);
    __syncthreads();
    cur ^= 1;
  }

  short* Cout = Cp + (size_t)z * M * N;
  const int rg = (lane >> 4) * 4;
#pragma unroll
  for (int m = 0; m < 4; m++) {
#pragma unroll
    for (int n = 0; n < 4; n++) {
      const int gcol = bn0 + wc * 64 + n * 16 + fr;
#pragma unroll
      for (int j = 0; j < 4; j++) {
        const int grow = bm0 + wr * 64 + m * 16 + rg + j;
        Cout[(size_t)grow * N + gcol] = f2bf(acc[m][n][j]);
      }
    }
  }
}

// ---------------- split-K reduce passes ----------------
// out_bf16 = p0 + p1 + bias (per column), vectorized 8-wide. exact grid.
__global__ __launch_bounds__(256) void reduce_bias_bf16(
    const short* __restrict__ Cp, const float* __restrict__ bias,
    short* __restrict__ out, size_t pstride, int ncol8) {
  const int i = blockIdx.x * blockDim.x + threadIdx.x;
  short8v a = ((const short8v*)Cp)[i];
  short8v b = ((const short8v*)(Cp + pstride))[i];
  const int col0 = (i % ncol8) * 8;
  const float4 b0 = *(const float4*)(bias + col0);
  const float4 b1 = *(const float4*)(bias + col0 + 4);
  short8v o;
  o[0] = f2bf(bf2f(a[0]) + bf2f(b[0]) + b0.x);
  o[1] = f2bf(bf2f(a[1]) + bf2f(b[1]) + b0.y);
  o[2] = f2bf(bf2f(a[2]) + bf2f(b[2]) + b0.z);
  o[3] = f2bf(bf2f(a[3]) + bf2f(b[3]) + b0.w);
  o[4] = f2bf(bf2f(a[4]) + bf2f(b[4]) + b1.x);
  o[5] = f2bf(bf2f(a[5]) + bf2f(b[5]) + b1.y);
  o[6] = f2bf(bf2f(a[6]) + bf2f(b[6]) + b1.z);
  o[7] = f2bf(bf2f(a[7]) + bf2f(b[7]) + b1.w);
  ((short8v*)out)[i] = o;
}

// out_f32 = p0 + p1 (final projection output). exact grid.
__global__ __launch_bounds__(256) void reduce_f32(
    const short* __restrict__ Cp, float* __restrict__ out, size_t pstride) {
  const int i = blockIdx.x * blockDim.x + threadIdx.x;
  short8v a = ((const short8v*)Cp)[i];
  short8v b = ((const short8v*)(Cp + pstride))[i];
  float4 o0, o1;
  o0.x = bf2f(a[0]) + bf2f(b[0]);
  o0.y = bf2f(a[1]) + bf2f(b[1]);
  o0.z = bf2f(a[2]) + bf2f(b[2]);
  o0.w = bf2f(a[3]) + bf2f(b[3]);
  o1.x = bf2f(a[4]) + bf2f(b[4]);
  o1.y = bf2f(a[5]) + bf2f(b[5]);
  o1.z = bf2f(a[6]) + bf2f(b[6]);
  o1.w = bf2f(a[7]) + bf2f(b[7]);
  ((float4*)out)[2 * i]     = o0;
  ((float4*)out)[2 * i + 1] = o1;
}

// ---------------- per-head RMSNorm + RoPE, 4 heads per 256-thread block -----
__global__ __launch_bounds__(256) void qkv_post_kernel(
    const short* __restrict__ qkvb,      // [T][4608] bf16 (bias included)
    const int*   __restrict__ positions,
    const float* __restrict__ q_ln,      // [128] f32
    const float* __restrict__ k_ln,      // [128] f32
    short* __restrict__ Qb,   // [NH][T][HD]
    short* __restrict__ Kb,   // [NKV][T][HD]
    short* __restrict__ Vt)   // [NKV][HD][T]
{
  const int t = blockIdx.x;
  const int h = blockIdx.y * 4 + (threadIdx.x >> 6);
  const int lane = threadIdx.x & 63;
  const unsigned int pk =
      ((const unsigned int*)(qkvb + (size_t)t * QKVN + h * HEADD))[lane];
  float x = bf2f((short)(pk & 0xffffu));
  float y = bf2f((short)(pk >> 16));

  if (h >= 34) { // V: transpose only
    const int hv = h - 34;
    short* dst = Vt + ((size_t)hv * HEADD + 2 * lane) * T_LEN + t;
    dst[0]     = f2bf(x);
    dst[T_LEN] = f2bf(y);
    return;
  }

  float ss = x * x + y * y;
#pragma unroll
  for (int d = 32; d > 0; d >>= 1) ss += __shfl_xor(ss, d);
  const float r = rsqrtf(ss * (1.0f / 128.0f) + 1e-5f);
  const float* lnw = (h < 32) ? q_ln : k_ln;
  x = x * r * lnw[2 * lane];
  y = y * r * lnw[2 * lane + 1];

  if (lane < 32) { // rotary pairs (2i,2i+1), i<32: ang = pos * 10000^(-i/32)
    const float pos = (float)positions[t];
    const float ang = pos * powf(10000.0f, -(float)lane * (1.0f / 32.0f));
    const float c = cosf(ang), s = sinf(ang);
    const float r1 = x * c - y * s;
    const float r2 = y * c + x * s;
    x = r1; y = r2;
  }

  short* dst = (h < 32) ? (Qb + ((size_t)h * T_LEN + t) * HEADD + 2 * lane)
                        : (Kb + ((size_t)(h - 32) * T_LEN + t) * HEADD + 2 * lane);
  dst[0] = f2bf(x);
  dst[1] = f2bf(y);
}

// ---------------- causal flash attention, GQA 16:1 ----------------
// R9 structure + T5 setprio; grid (16, 32, 2): z==0 attention, z==1 streams
// the w_dense f32->bf16 cast through attn's idle HBM (R16-measured).
__global__ __launch_bounds__(256, 2) void attn_kernel(
    const short* __restrict__ Qb,   // [NH][T][HD]
    const short* __restrict__ Kb,   // [NKV][T][HD]
    const short* __restrict__ Vt,   // [NKV][HD][T]
    short* __restrict__ attn_out,   // [T][NH*HD] bf16
    const float* __restrict__ wd_src,  // [H][H] f32
    short* __restrict__ wd_dst)        // [H][H] bf16
{
  __shared__ short Ks[2][64 * 128];   // [s][d] swizzled, 2x16KB
  __shared__ short Vs[2][128 * 64];   // [d][s] swizzled, 2x16KB
  __shared__ short pbuf[4][32 * 64];  // per-wave P tile [row][col] swizzled, 16KB
  const int tid  = threadIdx.x;

  if (blockIdx.z == 1) {   // trailing cast blocks
    const int bid = blockIdx.y * gridDim.x + blockIdx.x;
    const int stride = gridDim.x * gridDim.y * 256;
    const float4* s4 = (const float4*)wd_src;
    short4v* d4 = (short4v*)wd_dst;
    for (int i = bid * 256 + tid; i < (HDIM * HDIM) / 4; i += stride) {
      float4 v = s4[i];
      short4v o;
      o[0] = f2bf(v.x); o[1] = f2bf(v.y); o[2] = f2bf(v.z); o[3] = f2bf(v.w);
      d4[i] = o;
    }
    return;
  }

  const int blk  = gridDim.x - 1 - blockIdx.x;   // longest blocks first
  const int h    = blockIdx.y;
  const int hkv  = h >> 4;
  const int lane = tid & 63;
  const int wv   = tid >> 6;
  const int B0   = blk * 128;
  const int qrow0 = B0 + wv * 32;
  const int fr = lane & 15;
  const int fk = (lane >> 4) * 8;     // shorts
  const int fkb = (lane >> 4) << 4;   // bytes
  const int rg = (lane >> 4) * 4;
  const int swz = (fr & 7) << 4;

  const short* Kh = Kb + (size_t)hkv * T_LEN * HEADD;
  const short* Vh = Vt + (size_t)hkv * HEADD * T_LEN;

  short8v qf[2][4];
#pragma unroll
  for (int g = 0; g < 2; g++) {
    const short* Qrow = Qb + ((size_t)h * T_LEN + qrow0 + g * 16 + fr) * HEADD + fk;
#pragma unroll
    for (int d0 = 0; d0 < 4; d0++) qf[g][d0] = *(const short8v*)(Qrow + d0 * 32);
  }

  float mrow[2][4], lrow[2][4];
#pragma unroll
  for (int g = 0; g < 2; g++)
#pragma unroll
    for (int j = 0; j < 4; j++) { mrow[g][j] = -1e30f; lrow[g][j] = 0.f; }
  f32x4 zero = {0.f, 0.f, 0.f, 0.f};
  f32x4 o[2][8];
#pragma unroll
  for (int g = 0; g < 2; g++)
#pragma unroll
    for (int d = 0; d < 8; d++) o[g][d] = zero;

  char* pb = (char*)&pbuf[wv][0];
  const float scale = 0.08838834764831845f; // 128^-0.5
  const int nt = 2 * blk + 2;               // KV tiles of 64

  auto STAGE = [&](int b, int t) {
    const int s0 = t * 64;
#pragma unroll
    for (int i = 0; i < 4; i++) {          // K: [row s 0..63][col d], 256B rows
      const int c    = i * 256 + tid;
      const int row  = c >> 4;
      const int colb = (c & 15) << 4;
      const int scol = (colb ^ ((row & 7) << 4)) >> 1;
      gload_lds16(Kh + (size_t)(s0 + row) * HEADD + scol,
                  (char*)&Ks[b][0] + (size_t)(i * 256 + wv * 64) * 16);
    }
#pragma unroll
    for (int i = 0; i < 4; i++) {          // V: [row d 0..127][col s], 128B rows
      const int c    = i * 256 + tid;
      const int row  = c >> 3;
      const int colb = (c & 7) << 4;
      const int scol = (colb ^ ((row & 7) << 4)) >> 1;
      gload_lds16(Vh + (size_t)row * T_LEN + s0 + scol,
                  (char*)&Vs[b][0] + (size_t)(i * 256 + wv * 64) * 16);
    }
  };

  int cur = 0;
  STAGE(0, 0);
  __syncthreads();

  for (int t = 0; t < nt; ++t) {
    if (t + 1 < nt) STAGE(cur ^ 1, t + 1);
    const int s0 = t * 64;
    const char* KsB = (const char*)&Ks[cur][0];
    const char* VsB = (const char*)&Vs[cur][0];

    float scv[2][4][4];
    __builtin_amdgcn_s_setprio(1);
#pragma unroll
    for (int sub = 0; sub < 4; sub++) {
      const char* Kbase = KsB + (sub * 16 + fr) * 256;
      f32x4 a0 = zero, a1 = zero;
#pragma unroll
      for (int d0 = 0; d0 < 4; d0++) {
        short8v kf = *(const short8v*)(Kbase + ((d0 * 64 + fkb) ^ swz));
        a0 = __builtin_amdgcn_mfma_f32_16x16x32_bf16(qf[0][d0], kf, a0, 0, 0, 0);
        a1 = __builtin_amdgcn_mfma_f32_16x16x32_bf16(qf[1][d0], kf, a1, 0, 0, 0);
      }
#pragma unroll
      for (int j = 0; j < 4; j++) {
        scv[0][sub][j] = a0[j] * scale;
        scv[1][sub][j] = a1[j] * scale;
      }
    }
    __builtin_amdgcn_s_setprio(0);
    if (t >= nt - 2) {
#pragma unroll
      for (int g = 0; g < 2; g++)
#pragma unroll
        for (int sub = 0; sub < 4; sub++) {
          const int colp = s0 + sub * 16 + fr;
#pragma unroll
          for (int j = 0; j < 4; j++)
            if (colp > qrow0 + g * 16 + rg + j) scv[g][sub][j] = -1e30f;
        }
    }
    float pmax[2][4];
#pragma unroll
    for (int g = 0; g < 2; g++)
#pragma unroll
      for (int j = 0; j < 4; j++)
        pmax[g][j] = fmaxf(fmaxf(scv[g][0][j], scv[g][1][j]),
                           fmaxf(scv[g][2][j], scv[g][3][j]));
    float growth = -1e30f;
#pragma unroll
    for (int g = 0; g < 2; g++)
#pragma unroll
      for (int j = 0; j < 4; j++) growth = fmaxf(growth, pmax[g][j] - mrow[g][j]);
    if (!__all(growth <= 8.0f)) {
#pragma unroll
      for (int g = 0; g < 2; g++)
#pragma unroll
        for (int j = 0; j < 4; j++) {
          float mx = pmax[g][j];
#pragma unroll
          for (int d = 1; d < 16; d <<= 1) mx = fmaxf(mx, __shfl_xor(mx, d));
          const float mn = fmaxf(mrow[g][j], mx);
          const float c  = __expf(mrow[g][j] - mn);
          mrow[g][j] = mn;
          lrow[g][j] *= c;
#pragma unroll
          for (int df = 0; df < 8; df++) o[g][df][j] *= c;
        }
    }
#pragma unroll
    for (int g = 0; g < 2; g++)
#pragma unroll
      for (int j = 0; j < 4; j++) {
        const int prow = g * 16 + rg + j;
        char* prb = pb + prow * 128;
        const int rswz = ((rg + j) & 7) << 4;
        float ps = 0.f;
#pragma unroll
        for (int sub = 0; sub < 4; sub++) {
          const float p = __expf(scv[g][sub][j] - mrow[g][j]);
          ps += p;
          *(short*)(prb + ((((sub * 16 + fr) << 1)) ^ rswz)) = f2bf(p);
        }
        lrow[g][j] += ps;
      }
    asm volatile("" ::: "memory");
    short8v pf[2][2];
#pragma unroll
    for (int g = 0; g < 2; g++)
#pragma unroll
      for (int ks = 0; ks < 2; ks++)
        pf[g][ks] = *(const short8v*)(pb + (g * 16 + fr) * 128 + ((ks * 64 + fkb) ^ swz));
    __builtin_amdgcn_s_setprio(1);
#pragma unroll
    for (int df = 0; df < 8; df++) {
      const char* Vbase = VsB + (df * 16 + fr) * 128;
      short8v vf0 = *(const short8v*)(Vbase + ((0 + fkb) ^ swz));
      short8v vf1 = *(const short8v*)(Vbase + ((64 + fkb) ^ swz));
      o[0][df] = __builtin_amdgcn_mfma_f32_16x16x32_bf16(pf[0][0], vf0, o[0][df], 0, 0, 0);
      o[0][df] = __builtin_amdgcn_mfma_f32_16x16x32_bf16(pf[0][1], vf1, o[0][df], 0, 0, 0);
      o[1][df] = __builtin_amdgcn_mfma_f32_16x16x32_bf16(pf[1][0], vf0, o[1][df], 0, 0, 0);
      o[1][df] = __builtin_amdgcn_mfma_f32_16x16x32_bf16(pf[1][1], vf1, o[1][df], 0, 0, 0);
    }
    __builtin_amdgcn_s_setprio(0);
    __syncthreads();
    cur ^= 1;
  }

#pragma unroll
  for (int g = 0; g < 2; g++)
#pragma unroll
    for (int j = 0; j < 4; j++) {
#pragma unroll
      for (int d = 1; d < 16; d <<= 1) lrow[g][j] += __shfl_xor(lrow[g][j], d);
    }
#pragma unroll
  for (int g = 0; g < 2; g++)
#pragma unroll
    for (int df = 0; df < 8; df++)
#pragma unroll
      for (int j = 0; j < 4; j++) {
        const float v = o[g][df][j] / lrow[g][j];
        attn_out[(size_t)(qrow0 + g * 16 + rg + j) * HDIM + h * HEADD + df * 16 + fr] = f2bf(v);
      }
}

// ---------------- launch ----------------
extern "C" void kernel_launch(void* const* d_in, const int* in_sizes, int n_in,
                              void* d_out, int out_size, void* d_ws, size_t ws_size,
                              hipStream_t stream) {
  (void)out_size; (void)ws_size;
  // size-based input remap (robust to any d_in permutation; sizes are unique)
  int ip = 0, ih = 1, iwq = 2, ib = 3, iwd = 4, il0 = 5, il1 = 6;
  if (n_in == 7) {
    int p = -1, hh = -1, wq = -1, b = -1, wd = -1, l0 = -1, l1 = -1, ok = 1;
    for (int i = 0; i < 7; i++) {
      switch (in_sizes[i]) {
        case 2048:     p  = i; break;
        case 8388608:  hh = i; break;
        case 18874368: wq = i; break;
        case 4608:     b  = i; break;
        case 16777216: wd = i; break;
        case 128:      if (l0 < 0) l0 = i; else l1 = i; break;
        default:       ok = 0; break;
      }
    }
    if (ok && p >= 0 && hh >= 0 && wq >= 0 && b >= 0 && wd >= 0 && l0 >= 0 && l1 >= 0) {
      ip = p; ih = hh; iwq = wq; ib = b; iwd = wd; il0 = l0; il1 = l1;
    }
  }

  const int*   positions = (const int*)d_in[ip];
  const float* hidden    = (const float*)d_in[ih];
  const float* w_qkv     = (const float*)d_in[iwq];
  const float* b_qkv     = (const float*)d_in[ib];
  const float* w_dense   = (const float*)d_in[iwd];
  const float* q_ln      = (const float*)d_in[il0];
  const float* k_ln      = (const float*)d_in[il1];

  char* ws = (char*)d_ws;
  // lifetime-aliased workspace, peak exactly 92,274,688 B (R6-proven):
  //   phase1: Ahs[0,16.8M) Wqkv[16.8M,54.5M) Cp1[54.5M,92.3M)
  //   phase2: qkvb[0,18.9M) Qb[18.9M,35.7M) Kb Vt  (over dead Ahs/Wqkv)
  //   phase3: Wd[37.7M,71.3M) attnb[71.3M,88.1M)   (over dead Wqkv/Cp1)
  //   phase4: Cp2[0,33.6M)                          (over dead qkvb/Qb)
  short* Ahs   = (short*)(ws + 0);
  short* Wqkv  = (short*)(ws + (size_t)16777216);
  short* Cp1   = (short*)(ws + (size_t)54525952);   // 2 x 18,874,368 B
  short* qkvb  = (short*)(ws + 0);
  short* Qb    = (short*)(ws + (size_t)18874368);
  short* Kb    = (short*)(ws + (size_t)35651584);
  short* Vt    = (short*)(ws + (size_t)36700160);
  short* Wd    = (short*)(ws + (size_t)37748736);
  short* attnb = (short*)(ws + (size_t)71303168);
  short* Cp2   = (short*)(ws + 0);                  // 2 x 16,777,216 B

  cast_pair<<<dim3(3072), dim3(256), 0, stream>>>(
      hidden, Ahs, (T_LEN * HDIM) / 4, w_qkv, Wqkv, (QKVN * HDIM) / 4);
  gemm_splitk<<<dim3(QKVN / 128, T_LEN / 128, 2), dim3(256), 0, stream>>>(
      Ahs, Wqkv, Cp1, T_LEN, QKVN, HDIM);
  reduce_bias_bf16<<<dim3((T_LEN * QKVN) / 8 / 256), dim3(256), 0, stream>>>(
      Cp1, b_qkv, qkvb, (size_t)T_LEN * QKVN, QKVN / 8);
  qkv_post_kernel<<<dim3(T_LEN, 9), dim3(256), 0, stream>>>(
      qkvb, positions, q_ln, k_ln, Qb, Kb, Vt);
  attn_kernel<<<dim3(16, NHEADS, 2), dim3(256), 0, stream>>>(
      Qb, Kb, Vt, attnb, w_dense, Wd);
  gemm_splitk<<<dim3(HDIM / 128, T_LEN / 128, 2), dim3(256), 0, stream>>>(
      attnb, Wd, Cp2, T_LEN, HDIM, HDIM);
  reduce_f32<<<dim3((T_LEN * HDIM) / 8 / 256), dim3(256), 0, stream>>>(
      Cp2, (float*)d_out, (size_t)T_LEN * HDIM);
}

// Round 18
// 352.152 us; speedup vs baseline: 1.0831x; 1.0831x over previous
//
#include <hip/hip_runtime.h>
#include <cstdint>
#include <cstddef>

// ---------------- types ----------------
typedef short short4v __attribute__((ext_vector_type(4)));
typedef short short8v __attribute__((ext_vector_type(8)));
typedef float f32x4   __attribute__((ext_vector_type(4)));

#define T_LEN  2048
#define HDIM   4096
#define NHEADS 32
#define HEADD  128
#define QKVN   4608   // (32 + 2*2) * 128

static __device__ __forceinline__ short f2bf(float f) {
  __bf16 h = (__bf16)f;               // RNE fptrunc
  return __builtin_bit_cast(short, h);
}
static __device__ __forceinline__ float bf2f(short u) {
  return __builtin_bit_cast(float, ((unsigned int)(unsigned short)u) << 16);  // exact
}

static __device__ __forceinline__ void gload_lds16(const void* g, void* l) {
  // async global->LDS, 16B per lane; LDS dest is wave-uniform base + lane*16
  __builtin_amdgcn_global_load_lds((const __attribute__((address_space(1))) void*)g,
                                   (__attribute__((address_space(3))) void*)l,
                                   16, 0, 0);
}

// ---------------- cast f32 -> bf16 (vectorized, G13) ----------------
__global__ void cast_f32_to_bf16(const float* __restrict__ in, short* __restrict__ out, int n4) {
  int idx = blockIdx.x * blockDim.x + threadIdx.x;
  int stride = gridDim.x * blockDim.x;
  const float4* in4 = (const float4*)in;
  short4v* out4 = (short4v*)out;
  for (int i = idx; i < n4; i += stride) {
    float4 v = in4[i];
    short4v o;
    o[0] = f2bf(v.x); o[1] = f2bf(v.y); o[2] = f2bf(v.z); o[3] = f2bf(v.w);
    out4[i] = o;
  }
}

// ---------------- GEMM  C[M][N] = A[M][K] * B[N][K]^T (+bias) ---------------
// R9/R11-measured structure (113 us, best total): BK=32, single 16KB-per-
// operand LDS buffer, m97 2-barrier loop, 4 waves (2x2), 4x4 16x16x32 frags.
template <int OUT_BF16>
__global__ __launch_bounds__(256, 2) void gemm_bt(
    const short* __restrict__ A,     // [M][K] bf16
    const short* __restrict__ B,     // [N][K] bf16
    const float* __restrict__ bias,  // [N] f32 or nullptr
    void* __restrict__ Cout,         // [M][N] f32 or bf16
    int M, int N, int K)
{
  __shared__ short sA[128 * 32];
  __shared__ short sB[128 * 32];
  const int tid  = threadIdx.x;
  const int lane = tid & 63;
  const int wv   = tid >> 6;
  const int wr   = wv >> 1;
  const int wc   = wv & 1;
  const int bn0  = blockIdx.x * 128;
  const int bm0  = blockIdx.y * 128;

  const int row0 = tid >> 2;
  const int kc0  = (tid & 3) * 8;
  const int row1 = row0 + 64;
  short* lA0 = sA + wv * 64 * 8;
  short* lA1 = sA + (256 + wv * 64) * 8;
  short* lB0 = sB + wv * 64 * 8;
  short* lB1 = sB + (256 + wv * 64) * 8;
  const short* gA0 = A + (size_t)(bm0 + row0) * K + kc0;
  const short* gA1 = A + (size_t)(bm0 + row1) * K + kc0;
  const short* gB0 = B + (size_t)(bn0 + row0) * K + kc0;
  const short* gB1 = B + (size_t)(bn0 + row1) * K + kc0;

  const int fr = lane & 15;
  const int fk = (lane >> 4) * 8;

  f32x4 zero = {0.f, 0.f, 0.f, 0.f};
  f32x4 acc[4][4];
#pragma unroll
  for (int m = 0; m < 4; m++)
#pragma unroll
    for (int n = 0; n < 4; n++) acc[m][n] = zero;

  for (int kt = 0; kt < K; kt += 32) {
    gload_lds16(gA0 + kt, lA0);
    gload_lds16(gA1 + kt, lA1);
    gload_lds16(gB0 + kt, lB0);
    gload_lds16(gB1 + kt, lB1);
    __syncthreads();
    short8v af[4], bfr[4];
#pragma unroll
    for (int m = 0; m < 4; m++)
      af[m] = *(const short8v*)(sA + (wr * 64 + m * 16 + fr) * 32 + fk);
#pragma unroll
    for (int n = 0; n < 4; n++)
      bfr[n] = *(const short8v*)(sB + (wc * 64 + n * 16 + fr) * 32 + fk);
#pragma unroll
    for (int m = 0; m < 4; m++)
#pragma unroll
      for (int n = 0; n < 4; n++)
        acc[m][n] = __builtin_amdgcn_mfma_f32_16x16x32_bf16(af[m], bfr[n], acc[m][n], 0, 0, 0);
    __syncthreads();
  }

  // epilogue: C/D layout col=lane&15, row=(lane>>4)*4+j  [m89 verified]
  const int rg = (lane >> 4) * 4;
#pragma unroll
  for (int m = 0; m < 4; m++) {
#pragma unroll
    for (int n = 0; n < 4; n++) {
      const int gcol = bn0 + wc * 64 + n * 16 + fr;
      const float bv = bias ? bias[gcol] : 0.0f;
#pragma unroll
      for (int j = 0; j < 4; j++) {
        const int grow = bm0 + wr * 64 + m * 16 + rg + j;
        const float v = acc[m][n][j] + bv;
        if (OUT_BF16)
          ((short*)Cout)[(size_t)grow * N + gcol] = f2bf(v);
        else
          ((float*)Cout)[(size_t)grow * N + gcol] = v;
      }
    }
  }
}

// ---------------- per-head RMSNorm + RoPE + layout shuffle ----------------
__global__ __launch_bounds__(64) void qkv_post_kernel(
    const short* __restrict__ qkvb,      // [T][4608] bf16 (bias included)
    const int*   __restrict__ positions,
    const float* __restrict__ q_ln,      // [128] f32
    const float* __restrict__ k_ln,      // [128] f32
    short* __restrict__ Qb,   // [NH][T][HD]
    short* __restrict__ Kb,   // [NKV][T][HD]
    short* __restrict__ Vt)   // [NKV][HD][T]
{
  const int t = blockIdx.x;
  const int h = blockIdx.y;
  const int lane = threadIdx.x;
  const unsigned int pk =
      ((const unsigned int*)(qkvb + (size_t)t * QKVN + h * HEADD))[lane];
  float x = bf2f((short)(pk & 0xffffu));
  float y = bf2f((short)(pk >> 16));

  if (h >= 34) { // V: transpose only
    const int hv = h - 34;
    short* dst = Vt + ((size_t)hv * HEADD + 2 * lane) * T_LEN + t;
    dst[0]     = f2bf(x);
    dst[T_LEN] = f2bf(y);
    return;
  }

  float ss = x * x + y * y;
#pragma unroll
  for (int d = 32; d > 0; d >>= 1) ss += __shfl_xor(ss, d);
  const float r = rsqrtf(ss * (1.0f / 128.0f) + 1e-5f);
  const float* lnw = (h < 32) ? q_ln : k_ln;
  x = x * r * lnw[2 * lane];
  y = y * r * lnw[2 * lane + 1];

  if (lane < 32) { // rotary pairs (2i,2i+1), i<32: ang = pos * 10000^(-i/32)
    const float pos = (float)positions[t];
    const float ang = pos * powf(10000.0f, -(float)lane * (1.0f / 32.0f));
    const float c = cosf(ang), s = sinf(ang);
    const float r1 = x * c - y * s;
    const float r2 = y * c + x * s;
    x = r1; y = r2;
  }

  short* dst = (h < 32) ? (Qb + ((size_t)h * T_LEN + t) * HEADD + 2 * lane)
                        : (Kb + ((size_t)(h - 32) * T_LEN + t) * HEADD + 2 * lane);
  dst[0] = f2bf(x);
  dst[1] = f2bf(y);
}

// ---------------- causal flash attention, GQA 16:1 ----------------
// R9-measured structure: grid (16,32), 4 waves x 32 q-rows; XOR-swizzled
// K/V LDS staging (2-phase dbuf); defer-max softmax; per-lane denominator.
__global__ __launch_bounds__(256, 2) void attn_kernel(
    const short* __restrict__ Qb,   // [NH][T][HD]
    const short* __restrict__ Kb,   // [NKV][T][HD]
    const short* __restrict__ Vt,   // [NKV][HD][T]
    short* __restrict__ attn_out)   // [T][NH*HD] bf16
{
  __shared__ short Ks[2][64 * 128];   // [s][d] swizzled, 2x16KB
  __shared__ short Vs[2][128 * 64];   // [d][s] swizzled, 2x16KB
  __shared__ short pbuf[4][32 * 64];  // per-wave P tile [row][col] swizzled, 16KB
  const int blk  = gridDim.x - 1 - blockIdx.x;   // longest blocks first
  const int h    = blockIdx.y;
  const int hkv  = h >> 4;
  const int tid  = threadIdx.x;
  const int lane = tid & 63;
  const int wv   = tid >> 6;
  const int B0   = blk * 128;
  const int qrow0 = B0 + wv * 32;
  const int fr = lane & 15;
  const int fk = (lane >> 4) * 8;     // shorts
  const int fkb = (lane >> 4) << 4;   // bytes
  const int rg = (lane >> 4) * 4;
  const int swz = (fr & 7) << 4;

  const short* Kh = Kb + (size_t)hkv * T_LEN * HEADD;
  const short* Vh = Vt + (size_t)hkv * HEADD * T_LEN;

  short8v qf[2][4];
#pragma unroll
  for (int g = 0; g < 2; g++) {
    const short* Qrow = Qb + ((size_t)h * T_LEN + qrow0 + g * 16 + fr) * HEADD + fk;
#pragma unroll
    for (int d0 = 0; d0 < 4; d0++) qf[g][d0] = *(const short8v*)(Qrow + d0 * 32);
  }

  float mrow[2][4], lrow[2][4];
#pragma unroll
  for (int g = 0; g < 2; g++)
#pragma unroll
    for (int j = 0; j < 4; j++) { mrow[g][j] = -1e30f; lrow[g][j] = 0.f; }
  f32x4 zero = {0.f, 0.f, 0.f, 0.f};
  f32x4 o[2][8];
#pragma unroll
  for (int g = 0; g < 2; g++)
#pragma unroll
    for (int d = 0; d < 8; d++) o[g][d] = zero;

  char* pb = (char*)&pbuf[wv][0];
  const float scale = 0.08838834764831845f; // 128^-0.5
  const int nt = 2 * blk + 2;               // KV tiles of 64

  auto STAGE = [&](int b, int t) {
    const int s0 = t * 64;
#pragma unroll
    for (int i = 0; i < 4; i++) {          // K: [row s 0..63][col d], 256B rows
      const int c    = i * 256 + tid;
      const int row  = c >> 4;
      const int colb = (c & 15) << 4;
      const int scol = (colb ^ ((row & 7) << 4)) >> 1;
      gload_lds16(Kh + (size_t)(s0 + row) * HEADD + scol,
                  (char*)&Ks[b][0] + (size_t)(i * 256 + wv * 64) * 16);
    }
#pragma unroll
    for (int i = 0; i < 4; i++) {          // V: [row d 0..127][col s], 128B rows
      const int c    = i * 256 + tid;
      const int row  = c >> 3;
      const int colb = (c & 7) << 4;
      const int scol = (colb ^ ((row & 7) << 4)) >> 1;
      gload_lds16(Vh + (size_t)row * T_LEN + s0 + scol,
                  (char*)&Vs[b][0] + (size_t)(i * 256 + wv * 64) * 16);
    }
  };

  int cur = 0;
  STAGE(0, 0);
  __syncthreads();

  for (int t = 0; t < nt; ++t) {
    if (t + 1 < nt) STAGE(cur ^ 1, t + 1);
    const int s0 = t * 64;
    const char* KsB = (const char*)&Ks[cur][0];
    const char* VsB = (const char*)&Vs[cur][0];

    float scv[2][4][4];
#pragma unroll
    for (int sub = 0; sub < 4; sub++) {
      const char* Kbase = KsB + (sub * 16 + fr) * 256;
      f32x4 a0 = zero, a1 = zero;
#pragma unroll
      for (int d0 = 0; d0 < 4; d0++) {
        short8v kf = *(const short8v*)(Kbase + ((d0 * 64 + fkb) ^ swz));
        a0 = __builtin_amdgcn_mfma_f32_16x16x32_bf16(qf[0][d0], kf, a0, 0, 0, 0);
        a1 = __builtin_amdgcn_mfma_f32_16x16x32_bf16(qf[1][d0], kf, a1, 0, 0, 0);
      }
#pragma unroll
      for (int j = 0; j < 4; j++) {
        scv[0][sub][j] = a0[j] * scale;
        scv[1][sub][j] = a1[j] * scale;
      }
    }
    if (t >= nt - 2) {
#pragma unroll
      for (int g = 0; g < 2; g++)
#pragma unroll
        for (int sub = 0; sub < 4; sub++) {
          const int colp = s0 + sub * 16 + fr;
#pragma unroll
          for (int j = 0; j < 4; j++)
            if (colp > qrow0 + g * 16 + rg + j) scv[g][sub][j] = -1e30f;
        }
    }
    float pmax[2][4];
#pragma unroll
    for (int g = 0; g < 2; g++)
#pragma unroll
      for (int j = 0; j < 4; j++)
        pmax[g][j] = fmaxf(fmaxf(scv[g][0][j], scv[g][1][j]),
                           fmaxf(scv[g][2][j], scv[g][3][j]));
    float growth = -1e30f;
#pragma unroll
    for (int g = 0; g < 2; g++)
#pragma unroll
      for (int j = 0; j < 4; j++) growth = fmaxf(growth, pmax[g][j] - mrow[g][j]);
    if (!__all(growth <= 8.0f)) {
#pragma unroll
      for (int g = 0; g < 2; g++)
#pragma unroll
        for (int j = 0; j < 4; j++) {
          float mx = pmax[g][j];
#pragma unroll
          for (int d = 1; d < 16; d <<= 1) mx = fmaxf(mx, __shfl_xor(mx, d));
          const float mn = fmaxf(mrow[g][j], mx);
          const float c  = __expf(mrow[g][j] - mn);
          mrow[g][j] = mn;
          lrow[g][j] *= c;
#pragma unroll
          for (int df = 0; df < 8; df++) o[g][df][j] *= c;
        }
    }
#pragma unroll
    for (int g = 0; g < 2; g++)
#pragma unroll
      for (int j = 0; j < 4; j++) {
        const int prow = g * 16 + rg + j;
        char* prb = pb + prow * 128;
        const int rswz = ((rg + j) & 7) << 4;
        float ps = 0.f;
#pragma unroll
        for (int sub = 0; sub < 4; sub++) {
          const float p = __expf(scv[g][sub][j] - mrow[g][j]);
          ps += p;
          *(short*)(prb + ((((sub * 16 + fr) << 1)) ^ rswz)) = f2bf(p);
        }
        lrow[g][j] += ps;
      }
    asm volatile("" ::: "memory");
    short8v pf[2][2];
#pragma unroll
    for (int g = 0; g < 2; g++)
#pragma unroll
      for (int ks = 0; ks < 2; ks++)
        pf[g][ks] = *(const short8v*)(pb + (g * 16 + fr) * 128 + ((ks * 64 + fkb) ^ swz));
#pragma unroll
    for (int df = 0; df < 8; df++) {
      const char* Vbase = VsB + (df * 16 + fr) * 128;
      short8v vf0 = *(const short8v*)(Vbase + ((0 + fkb) ^ swz));
      short8v vf1 = *(const short8v*)(Vbase + ((64 + fkb) ^ swz));
      o[0][df] = __builtin_amdgcn_mfma_f32_16x16x32_bf16(pf[0][0], vf0, o[0][df], 0, 0, 0);
      o[0][df] = __builtin_amdgcn_mfma_f32_16x16x32_bf16(pf[0][1], vf1, o[0][df], 0, 0, 0);
      o[1][df] = __builtin_amdgcn_mfma_f32_16x16x32_bf16(pf[1][0], vf0, o[1][df], 0, 0, 0);
      o[1][df] = __builtin_amdgcn_mfma_f32_16x16x32_bf16(pf[1][1], vf1, o[1][df], 0, 0, 0);
    }
    __syncthreads();
    cur ^= 1;
  }

#pragma unroll
  for (int g = 0; g < 2; g++)
#pragma unroll
    for (int j = 0; j < 4; j++) {
#pragma unroll
      for (int d = 1; d < 16; d <<= 1) lrow[g][j] += __shfl_xor(lrow[g][j], d);
    }
#pragma unroll
  for (int g = 0; g < 2; g++)
#pragma unroll
    for (int df = 0; df < 8; df++)
#pragma unroll
      for (int j = 0; j < 4; j++) {
        const float v = o[g][df][j] / lrow[g][j];
        attn_out[(size_t)(qrow0 + g * 16 + rg + j) * HDIM + h * HEADD + df * 16 + fr] = f2bf(v);
      }
}

// ---------------- launch ----------------
extern "C" void kernel_launch(void* const* d_in, const int* in_sizes, int n_in,
                              void* d_out, int out_size, void* d_ws, size_t ws_size,
                              hipStream_t stream) {
  (void)out_size; (void)ws_size;
  // size-based input remap (robust to any d_in permutation; sizes are unique)
  int ip = 0, ih = 1, iwq = 2, ib = 3, iwd = 4, il0 = 5, il1 = 6;
  if (n_in == 7) {
    int p = -1, hh = -1, wq = -1, b = -1, wd = -1, l0 = -1, l1 = -1, ok = 1;
    for (int i = 0; i < 7; i++) {
      switch (in_sizes[i]) {
        case 2048:     p  = i; break;
        case 8388608:  hh = i; break;
        case 18874368: wq = i; break;
        case 4608:     b  = i; break;
        case 16777216: wd = i; break;
        case 128:      if (l0 < 0) l0 = i; else l1 = i; break;
        default:       ok = 0; break;
      }
    }
    if (ok && p >= 0 && hh >= 0 && wq >= 0 && b >= 0 && wd >= 0 && l0 >= 0 && l1 >= 0) {
      ip = p; ih = hh; iwq = wq; ib = b; iwd = wd; il0 = l0; il1 = l1;
    }
  }

  const int*   positions = (const int*)d_in[ip];
  const float* hidden    = (const float*)d_in[ih];
  const float* w_qkv     = (const float*)d_in[iwq];
  const float* b_qkv     = (const float*)d_in[ib];
  const float* w_dense   = (const float*)d_in[iwd];
  const float* q_ln      = (const float*)d_in[il0];
  const float* k_ln      = (const float*)d_in[il1];

  char* ws = (char*)d_ws;
  // lifetime-aliased workspace (peak ~73.4 MB):
  short* Ahs   = (short*)(ws + 0);                   // 16.8 MB (dead after gemm1)
  short* Qb    = (short*)(ws + 0);                   // 16.8 MB (aliases Ahs)
  short* Wqkv  = (short*)(ws + (size_t)16777216);    // 37.7 MB (dead after gemm1)
  short* Kb    = (short*)(ws + (size_t)16777216);    // 1.0 MB  (aliases Wqkv)
  short* Vt    = (short*)(ws + (size_t)17825792);    // 1.0 MB  (aliases Wqkv)
  short* Wd    = (short*)(ws + (size_t)18874368);    // 33.5 MB (aliases Wqkv)
  short* qkvb  = (short*)(ws + (size_t)54525952);    // 18.9 MB bf16 (dead after qkv_post)
  short* attnb = (short*)(ws + (size_t)54525952);    // 16.8 MB (aliases qkvb)

  cast_f32_to_bf16<<<dim3(1024), dim3(256), 0, stream>>>(hidden, Ahs, (T_LEN * HDIM) / 4);
  cast_f32_to_bf16<<<dim3(2048), dim3(256), 0, stream>>>(w_qkv, Wqkv, (QKVN * HDIM) / 4);
  gemm_bt<1><<<dim3(QKVN / 128, T_LEN / 128), dim3(256), 0, stream>>>(
      Ahs, Wqkv, b_qkv, (void*)qkvb, T_LEN, QKVN, HDIM);
  qkv_post_kernel<<<dim3(T_LEN, 36), dim3(64), 0, stream>>>(
      qkvb, positions, q_ln, k_ln, Qb, Kb, Vt);
  cast_f32_to_bf16<<<dim3(2048), dim3(256), 0, stream>>>(w_dense, Wd, (HDIM * HDIM) / 4);
  attn_kernel<<<dim3(16, NHEADS), dim3(256), 0, stream>>>(Qb, Kb, Vt, attnb);
  gemm_bt<0><<<dim3(HDIM / 128, T_LEN / 128), dim3(256), 0, stream>>>(
      attnb, Wd, nullptr, d_out, T_LEN, HDIM, HDIM);
}

// Round 19
// 324.662 us; speedup vs baseline: 1.1748x; 1.0847x over previous
//
#include <hip/hip_runtime.h>
#include <cstdint>
#include <cstddef>

// ---------------- types ----------------
typedef short short4v __attribute__((ext_vector_type(4)));
typedef short short8v __attribute__((ext_vector_type(8)));
typedef float f32x4   __attribute__((ext_vector_type(4)));

#define T_LEN  2048
#define HDIM   4096
#define NHEADS 32
#define HEADD  128
#define QKVN   4608   // (32 + 2*2) * 128

static __device__ __forceinline__ short f2bf(float f) {
  __bf16 h = (__bf16)f;               // RNE fptrunc
  return __builtin_bit_cast(short, h);
}
static __device__ __forceinline__ float bf2f(short u) {
  return __builtin_bit_cast(float, ((unsigned int)(unsigned short)u) << 16);  // exact
}

static __device__ __forceinline__ void gload_lds16(const void* g, void* l) {
  // async global->LDS, 16B per lane; LDS dest is wave-uniform base + lane*16
  __builtin_amdgcn_global_load_lds((const __attribute__((address_space(1))) void*)g,
                                   (__attribute__((address_space(3))) void*)l,
                                   16, 0, 0);
}

// ---------------- cast f32 -> bf16 (vectorized, G13) ----------------
__global__ void cast_f32_to_bf16(const float* __restrict__ in, short* __restrict__ out, int n4) {
  int idx = blockIdx.x * blockDim.x + threadIdx.x;
  int stride = gridDim.x * blockDim.x;
  const float4* in4 = (const float4*)in;
  short4v* out4 = (short4v*)out;
  for (int i = idx; i < n4; i += stride) {
    float4 v = in4[i];
    short4v o;
    o[0] = f2bf(v.x); o[1] = f2bf(v.y); o[2] = f2bf(v.z); o[3] = f2bf(v.w);
    out4[i] = o;
  }
}

// ---------------- GEMM  C[M][N] = A[M][K] * B[N][K]^T (+bias) ---------------
// BK=64 SINGLE-buffer (32KB -> 2 blocks/CU preserved): halves the number of
// per-K-tile latency-drain events vs BK=32 at unchanged per-wave MFMA density.
// 128B LDS rows require the rule-#21 XOR swizzle (linear would be 16-way
// conflict, m201): inverse-swizzled global source + linear gload_lds dest +
// same XOR on ds_read (R10-verified index math). T1 bijective XCD swizzle.
template <int OUT_BF16>
__global__ __launch_bounds__(256, 2) void gemm_bt(
    const short* __restrict__ A,     // [M][K] bf16
    const short* __restrict__ B,     // [N][K] bf16
    const float* __restrict__ bias,  // [N] f32 or nullptr
    void* __restrict__ Cout,         // [M][N] f32 or bf16
    int M, int N, int K)
{
  __shared__ short sA[128 * 64];   // [row][k] 128B rows, swizzled, 16KB
  __shared__ short sB[128 * 64];
  const int tid  = threadIdx.x;
  const int lane = tid & 63;
  const int wv   = tid >> 6;
  const int wr   = wv >> 1;
  const int wc   = wv & 1;

  // T1: bijective XCD chunking (nwg % 8 == 0 for our grids)
  const int nwg  = gridDim.x * gridDim.y;
  int wgid = blockIdx.y * gridDim.x + blockIdx.x;
  wgid = (wgid & 7) * (nwg >> 3) + (wgid >> 3);
  const int bn0 = (wgid / gridDim.y) * 128;
  const int bm0 = (wgid % gridDim.y) * 128;

  const int fr  = lane & 15;          // fragment row/col
  const int fkb = (lane >> 4) << 4;   // fragment k offset, bytes
  const int swz = (fr & 7) << 4;      // read-side XOR

  // staging geometry (R10-verified): 32 rows per 256-thread issue, 8 slots/row
  const int c_row  = tid >> 3;              // 0..31
  const int c_colb = (tid & 7) << 4;        // logical col bytes 0..112
  const int c_scol = (c_colb ^ ((c_row & 7) << 4)) >> 1;  // inverse-swz src col (shorts)

  // stage one BK=64 tile: 4 issues A + 4 issues B (128 rows x 128B each)
  auto STAGE = [&](int kt) {
#pragma unroll
    for (int i = 0; i < 4; i++) {
      const int row = i * 32 + c_row;       // (row&7)==(c_row&7): i*32 % 8 == 0
      gload_lds16(A + (size_t)(bm0 + row) * K + kt + c_scol,
                  (char*)sA + (size_t)(i * 256 + wv * 64) * 16);
      gload_lds16(B + (size_t)(bn0 + row) * K + kt + c_scol,
                  (char*)sB + (size_t)(i * 256 + wv * 64) * 16);
    }
  };

  f32x4 zero = {0.f, 0.f, 0.f, 0.f};
  f32x4 acc[4][4];
#pragma unroll
  for (int m = 0; m < 4; m++)
#pragma unroll
    for (int n = 0; n < 4; n++) acc[m][n] = zero;

  for (int kt = 0; kt < K; kt += 64) {
    STAGE(kt);
    __syncthreads();   // drains vmcnt -> tile ready
    const char* aB = (const char*)sA;
    const char* bB = (const char*)sB;
#pragma unroll
    for (int ks = 0; ks < 2; ks++) {       // k-halves in ascending order
      short8v af[4], bfr[4];
#pragma unroll
      for (int m = 0; m < 4; m++) {
        const int row = wr * 64 + m * 16 + fr;
        af[m] = *(const short8v*)(aB + row * 128 + ((ks * 64 + fkb) ^ swz));
      }
#pragma unroll
      for (int n = 0; n < 4; n++) {
        const int row = wc * 64 + n * 16 + fr;
        bfr[n] = *(const short8v*)(bB + row * 128 + ((ks * 64 + fkb) ^ swz));
      }
#pragma unroll
      for (int m = 0; m < 4; m++)
#pragma unroll
        for (int n = 0; n < 4; n++)
          acc[m][n] = __builtin_amdgcn_mfma_f32_16x16x32_bf16(af[m], bfr[n], acc[m][n], 0, 0, 0);
    }
    __syncthreads();   // all waves done reading before next stage overwrites
  }

  // epilogue: C/D layout col=lane&15, row=(lane>>4)*4+j  [m89 verified]
  const int rg = (lane >> 4) * 4;
#pragma unroll
  for (int m = 0; m < 4; m++) {
#pragma unroll
    for (int n = 0; n < 4; n++) {
      const int gcol = bn0 + wc * 64 + n * 16 + fr;
      const float bv = bias ? bias[gcol] : 0.0f;
#pragma unroll
      for (int j = 0; j < 4; j++) {
        const int grow = bm0 + wr * 64 + m * 16 + rg + j;
        const float v = acc[m][n][j] + bv;
        if (OUT_BF16)
          ((short*)Cout)[(size_t)grow * N + gcol] = f2bf(v);
        else
          ((float*)Cout)[(size_t)grow * N + gcol] = v;
      }
    }
  }
}

// ---------------- per-head RMSNorm + RoPE + layout shuffle ----------------
__global__ __launch_bounds__(64) void qkv_post_kernel(
    const short* __restrict__ qkvb,      // [T][4608] bf16 (bias included)
    const int*   __restrict__ positions,
    const float* __restrict__ q_ln,      // [128] f32
    const float* __restrict__ k_ln,      // [128] f32
    short* __restrict__ Qb,   // [NH][T][HD]
    short* __restrict__ Kb,   // [NKV][T][HD]
    short* __restrict__ Vt)   // [NKV][HD][T]
{
  const int t = blockIdx.x;
  const int h = blockIdx.y;
  const int lane = threadIdx.x;
  const unsigned int pk =
      ((const unsigned int*)(qkvb + (size_t)t * QKVN + h * HEADD))[lane];
  float x = bf2f((short)(pk & 0xffffu));
  float y = bf2f((short)(pk >> 16));

  if (h >= 34) { // V: transpose only
    const int hv = h - 34;
    short* dst = Vt + ((size_t)hv * HEADD + 2 * lane) * T_LEN + t;
    dst[0]     = f2bf(x);
    dst[T_LEN] = f2bf(y);
    return;
  }

  float ss = x * x + y * y;
#pragma unroll
  for (int d = 32; d > 0; d >>= 1) ss += __shfl_xor(ss, d);
  const float r = rsqrtf(ss * (1.0f / 128.0f) + 1e-5f);
  const float* lnw = (h < 32) ? q_ln : k_ln;
  x = x * r * lnw[2 * lane];
  y = y * r * lnw[2 * lane + 1];

  if (lane < 32) { // rotary pairs (2i,2i+1), i<32: ang = pos * 10000^(-i/32)
    const float pos = (float)positions[t];
    const float ang = pos * powf(10000.0f, -(float)lane * (1.0f / 32.0f));
    const float c = cosf(ang), s = sinf(ang);
    const float r1 = x * c - y * s;
    const float r2 = y * c + x * s;
    x = r1; y = r2;
  }

  short* dst = (h < 32) ? (Qb + ((size_t)h * T_LEN + t) * HEADD + 2 * lane)
                        : (Kb + ((size_t)(h - 32) * T_LEN + t) * HEADD + 2 * lane);
  dst[0] = f2bf(x);
  dst[1] = f2bf(y);
}

// ---------------- causal flash attention, GQA 16:1 ----------------
// R9-measured structure (unchanged).
__global__ __launch_bounds__(256, 2) void attn_kernel(
    const short* __restrict__ Qb,   // [NH][T][HD]
    const short* __restrict__ Kb,   // [NKV][T][HD]
    const short* __restrict__ Vt,   // [NKV][HD][T]
    short* __restrict__ attn_out)   // [T][NH*HD] bf16
{
  __shared__ short Ks[2][64 * 128];   // [s][d] swizzled, 2x16KB
  __shared__ short Vs[2][128 * 64];   // [d][s] swizzled, 2x16KB
  __shared__ short pbuf[4][32 * 64];  // per-wave P tile [row][col] swizzled, 16KB
  const int blk  = gridDim.x - 1 - blockIdx.x;   // longest blocks first
  const int h    = blockIdx.y;
  const int hkv  = h >> 4;
  const int tid  = threadIdx.x;
  const int lane = tid & 63;
  const int wv   = tid >> 6;
  const int B0   = blk * 128;
  const int qrow0 = B0 + wv * 32;
  const int fr = lane & 15;
  const int fk = (lane >> 4) * 8;     // shorts
  const int fkb = (lane >> 4) << 4;   // bytes
  const int rg = (lane >> 4) * 4;
  const int swz = (fr & 7) << 4;

  const short* Kh = Kb + (size_t)hkv * T_LEN * HEADD;
  const short* Vh = Vt + (size_t)hkv * HEADD * T_LEN;

  short8v qf[2][4];
#pragma unroll
  for (int g = 0; g < 2; g++) {
    const short* Qrow = Qb + ((size_t)h * T_LEN + qrow0 + g * 16 + fr) * HEADD + fk;
#pragma unroll
    for (int d0 = 0; d0 < 4; d0++) qf[g][d0] = *(const short8v*)(Qrow + d0 * 32);
  }

  float mrow[2][4], lrow[2][4];
#pragma unroll
  for (int g = 0; g < 2; g++)
#pragma unroll
    for (int j = 0; j < 4; j++) { mrow[g][j] = -1e30f; lrow[g][j] = 0.f; }
  f32x4 zero = {0.f, 0.f, 0.f, 0.f};
  f32x4 o[2][8];
#pragma unroll
  for (int g = 0; g < 2; g++)
#pragma unroll
    for (int d = 0; d < 8; d++) o[g][d] = zero;

  char* pb = (char*)&pbuf[wv][0];
  const float scale = 0.08838834764831845f; // 128^-0.5
  const int nt = 2 * blk + 2;               // KV tiles of 64

  auto STAGE = [&](int b, int t) {
    const int s0 = t * 64;
#pragma unroll
    for (int i = 0; i < 4; i++) {          // K: [row s 0..63][col d], 256B rows
      const int c    = i * 256 + tid;
      const int row  = c >> 4;
      const int colb = (c & 15) << 4;
      const int scol = (colb ^ ((row & 7) << 4)) >> 1;
      gload_lds16(Kh + (size_t)(s0 + row) * HEADD + scol,
                  (char*)&Ks[b][0] + (size_t)(i * 256 + wv * 64) * 16);
    }
#pragma unroll
    for (int i = 0; i < 4; i++) {          // V: [row d 0..127][col s], 128B rows
      const int c    = i * 256 + tid;
      const int row  = c >> 3;
      const int colb = (c & 7) << 4;
      const int scol = (colb ^ ((row & 7) << 4)) >> 1;
      gload_lds16(Vh + (size_t)row * T_LEN + s0 + scol,
                  (char*)&Vs[b][0] + (size_t)(i * 256 + wv * 64) * 16);
    }
  };

  int cur = 0;
  STAGE(0, 0);
  __syncthreads();

  for (int t = 0; t < nt; ++t) {
    if (t + 1 < nt) STAGE(cur ^ 1, t + 1);
    const int s0 = t * 64;
    const char* KsB = (const char*)&Ks[cur][0];
    const char* VsB = (const char*)&Vs[cur][0];

    float scv[2][4][4];
#pragma unroll
    for (int sub = 0; sub < 4; sub++) {
      const char* Kbase = KsB + (sub * 16 + fr) * 256;
      f32x4 a0 = zero, a1 = zero;
#pragma unroll
      for (int d0 = 0; d0 < 4; d0++) {
        short8v kf = *(const short8v*)(Kbase + ((d0 * 64 + fkb) ^ swz));
        a0 = __builtin_amdgcn_mfma_f32_16x16x32_bf16(qf[0][d0], kf, a0, 0, 0, 0);
        a1 = __builtin_amdgcn_mfma_f32_16x16x32_bf16(qf[1][d0], kf, a1, 0, 0, 0);
      }
#pragma unroll
      for (int j = 0; j < 4; j++) {
        scv[0][sub][j] = a0[j] * scale;
        scv[1][sub][j] = a1[j] * scale;
      }
    }
    if (t >= nt - 2) {
#pragma unroll
      for (int g = 0; g < 2; g++)
#pragma unroll
        for (int sub = 0; sub < 4; sub++) {
          const int colp = s0 + sub * 16 + fr;
#pragma unroll
          for (int j = 0; j < 4; j++)
            if (colp > qrow0 + g * 16 + rg + j) scv[g][sub][j] = -1e30f;
        }
    }
    float pmax[2][4];
#pragma unroll
    for (int g = 0; g < 2; g++)
#pragma unroll
      for (int j = 0; j < 4; j++)
        pmax[g][j] = fmaxf(fmaxf(scv[g][0][j], scv[g][1][j]),
                           fmaxf(scv[g][2][j], scv[g][3][j]));
    float growth = -1e30f;
#pragma unroll
    for (int g = 0; g < 2; g++)
#pragma unroll
      for (int j = 0; j < 4; j++) growth = fmaxf(growth, pmax[g][j] - mrow[g][j]);
    if (!__all(growth <= 8.0f)) {
#pragma unroll
      for (int g = 0; g < 2; g++)
#pragma unroll
        for (int j = 0; j < 4; j++) {
          float mx = pmax[g][j];
#pragma unroll
          for (int d = 1; d < 16; d <<= 1) mx = fmaxf(mx, __shfl_xor(mx, d));
          const float mn = fmaxf(mrow[g][j], mx);
          const float c  = __expf(mrow[g][j] - mn);
          mrow[g][j] = mn;
          lrow[g][j] *= c;
#pragma unroll
          for (int df = 0; df < 8; df++) o[g][df][j] *= c;
        }
    }
#pragma unroll
    for (int g = 0; g < 2; g++)
#pragma unroll
      for (int j = 0; j < 4; j++) {
        const int prow = g * 16 + rg + j;
        char* prb = pb + prow * 128;
        const int rswz = ((rg + j) & 7) << 4;
        float ps = 0.f;
#pragma unroll
        for (int sub = 0; sub < 4; sub++) {
          const float p = __expf(scv[g][sub][j] - mrow[g][j]);
          ps += p;
          *(short*)(prb + ((((sub * 16 + fr) << 1)) ^ rswz)) = f2bf(p);
        }
        lrow[g][j] += ps;
      }
    asm volatile("" ::: "memory");
    short8v pf[2][2];
#pragma unroll
    for (int g = 0; g < 2; g++)
#pragma unroll
      for (int ks = 0; ks < 2; ks++)
        pf[g][ks] = *(const short8v*)(pb + (g * 16 + fr) * 128 + ((ks * 64 + fkb) ^ swz));
#pragma unroll
    for (int df = 0; df < 8; df++) {
      const char* Vbase = VsB + (df * 16 + fr) * 128;
      short8v vf0 = *(const short8v*)(Vbase + ((0 + fkb) ^ swz));
      short8v vf1 = *(const short8v*)(Vbase + ((64 + fkb) ^ swz));
      o[0][df] = __builtin_amdgcn_mfma_f32_16x16x32_bf16(pf[0][0], vf0, o[0][df], 0, 0, 0);
      o[0][df] = __builtin_amdgcn_mfma_f32_16x16x32_bf16(pf[0][1], vf1, o[0][df], 0, 0, 0);
      o[1][df] = __builtin_amdgcn_mfma_f32_16x16x32_bf16(pf[1][0], vf0, o[1][df], 0, 0, 0);
      o[1][df] = __builtin_amdgcn_mfma_f32_16x16x32_bf16(pf[1][1], vf1, o[1][df], 0, 0, 0);
    }
    __syncthreads();
    cur ^= 1;
  }

#pragma unroll
  for (int g = 0; g < 2; g++)
#pragma unroll
    for (int j = 0; j < 4; j++) {
#pragma unroll
      for (int d = 1; d < 16; d <<= 1) lrow[g][j] += __shfl_xor(lrow[g][j], d);
    }
#pragma unroll
  for (int g = 0; g < 2; g++)
#pragma unroll
    for (int df = 0; df < 8; df++)
#pragma unroll
      for (int j = 0; j < 4; j++) {
        const float v = o[g][df][j] / lrow[g][j];
        attn_out[(size_t)(qrow0 + g * 16 + rg + j) * HDIM + h * HEADD + df * 16 + fr] = f2bf(v);
      }
}

// ---------------- launch ----------------
extern "C" void kernel_launch(void* const* d_in, const int* in_sizes, int n_in,
                              void* d_out, int out_size, void* d_ws, size_t ws_size,
                              hipStream_t stream) {
  (void)out_size; (void)ws_size;
  // size-based input remap (robust to any d_in permutation; sizes are unique)
  int ip = 0, ih = 1, iwq = 2, ib = 3, iwd = 4, il0 = 5, il1 = 6;
  if (n_in == 7) {
    int p = -1, hh = -1, wq = -1, b = -1, wd = -1, l0 = -1, l1 = -1, ok = 1;
    for (int i = 0; i < 7; i++) {
      switch (in_sizes[i]) {
        case 2048:     p  = i; break;
        case 8388608:  hh = i; break;
        case 18874368: wq = i; break;
        case 4608:     b  = i; break;
        case 16777216: wd = i; break;
        case 128:      if (l0 < 0) l0 = i; else l1 = i; break;
        default:       ok = 0; break;
      }
    }
    if (ok && p >= 0 && hh >= 0 && wq >= 0 && b >= 0 && wd >= 0 && l0 >= 0 && l1 >= 0) {
      ip = p; ih = hh; iwq = wq; ib = b; iwd = wd; il0 = l0; il1 = l1;
    }
  }

  const int*   positions = (const int*)d_in[ip];
  const float* hidden    = (const float*)d_in[ih];
  const float* w_qkv     = (const float*)d_in[iwq];
  const float* b_qkv     = (const float*)d_in[ib];
  const float* w_dense   = (const float*)d_in[iwd];
  const float* q_ln      = (const float*)d_in[il0];
  const float* k_ln      = (const float*)d_in[il1];

  char* ws = (char*)d_ws;
  // lifetime-aliased workspace (peak ~73.4 MB):
  short* Ahs   = (short*)(ws + 0);                   // 16.8 MB (dead after gemm1)
  short* Qb    = (short*)(ws + 0);                   // 16.8 MB (aliases Ahs)
  short* Wqkv  = (short*)(ws + (size_t)16777216);    // 37.7 MB (dead after gemm1)
  short* Kb    = (short*)(ws + (size_t)16777216);    // 1.0 MB  (aliases Wqkv)
  short* Vt    = (short*)(ws + (size_t)17825792);    // 1.0 MB  (aliases Wqkv)
  short* Wd    = (short*)(ws + (size_t)18874368);    // 33.5 MB (aliases Wqkv)
  short* qkvb  = (short*)(ws + (size_t)54525952);    // 18.9 MB bf16 (dead after qkv_post)
  short* attnb = (short*)(ws + (size_t)54525952);    // 16.8 MB (aliases qkvb)

  cast_f32_to_bf16<<<dim3(1024), dim3(256), 0, stream>>>(hidden, Ahs, (T_LEN * HDIM) / 4);
  cast_f32_to_bf16<<<dim3(2048), dim3(256), 0, stream>>>(w_qkv, Wqkv, (QKVN * HDIM) / 4);
  gemm_bt<1><<<dim3(QKVN / 128, T_LEN / 128), dim3(256), 0, stream>>>(
      Ahs, Wqkv, b_qkv, (void*)qkvb, T_LEN, QKVN, HDIM);
  qkv_post_kernel<<<dim3(T_LEN, 36), dim3(64), 0, stream>>>(
      qkvb, positions, q_ln, k_ln, Qb, Kb, Vt);
  cast_f32_to_bf16<<<dim3(2048), dim3(256), 0, stream>>>(w_dense, Wd, (HDIM * HDIM) / 4);
  attn_kernel<<<dim3(16, NHEADS), dim3(256), 0, stream>>>(Qb, Kb, Vt, attnb);
  gemm_bt<0><<<dim3(HDIM / 128, T_LEN / 128), dim3(256), 0, stream>>>(
      attnb, Wd, nullptr, d_out, T_LEN, HDIM, HDIM);
}